// Round 3
// baseline (69.326 us; speedup 1.0000x reference)
//
#include <hip/hip_runtime.h>

#define BB 16
#define HH 4
#define TT 1024
#define DD 512
#define NTAP 9
#define CHUNK 128
#define LOOKBACK 256

// One thread per (b,h,d) channel. T split into 8 chunks of 128 with a
// 256-step zero-state warmup (contracting recurrence; measured truncation
// error 0.0156 << 0.121 threshold). 4096 waves = 4 waves/SIMD for latency
// hiding. 16-deep double-buffered register prefetch of v; static-index
// circular history (rule #20).

#define DFSMN_BLOCK(CUR, NXT, TB, STORE)                                     \
  {                                                                          \
    _Pragma("unroll")                                                        \
    for (int u = 0; u < 16; ++u) {                                           \
      const int idx = (TB) + 18 + u;                                         \
      NXT[u] = (idx < TT) ? vp[(size_t)idx * DD] : 0.0f;                     \
    }                                                                        \
    _Pragma("unroll")                                                        \
    for (int u = 0; u < 16; ++u) {                                           \
      const float vt  = (u == 0) ? w0 : ((u == 1) ? w1 : CUR[(u < 2) ? 0 : (u - 2)]); \
      const float vt1 = (u == 0) ? w1 : CUR[(u < 1) ? 0 : (u - 1)];          \
      const float vt2 = CUR[u];                                              \
      float p = fmaf(vt, c0, r0 * vt1);                                      \
      p = fmaf(r1, vt2, p);                                                  \
      /* oldest tap first: p[t-1] dependency stays the LAST fma */           \
      _Pragma("unroll")                                                      \
      for (int k = NTAP - 1; k >= 0; --k)                                    \
        p = fmaf(a[k], hist[(u + 15 - k) & 15], p);                          \
      hist[u & 15] = p;                                                      \
      if (STORE) __builtin_nontemporal_store(p, &op[(size_t)((TB) + u) * DD]); \
    }                                                                        \
    w0 = CUR[14];                                                            \
    w1 = CUR[15];                                                            \
  }

__global__ __launch_bounds__(256, 2) void dfsmn_kernel(
    const float* __restrict__ v,
    const float* __restrict__ lfilt,
    const float* __restrict__ rfilt,
    float* __restrict__ out)
{
    const int d  = blockIdx.x * 256 + threadIdx.x;   // 0..511
    const int bh = blockIdx.y;                       // 0..63
    const int t_begin = blockIdx.z * CHUNK;
    const int t_end   = t_begin + CHUNK;
    const int ts = (t_begin >= LOOKBACK) ? (t_begin - LOOKBACK) : 0;

    const float* __restrict__ vp = v + (size_t)bh * TT * DD + d;
    float* __restrict__ op = out + (size_t)bh * TT * DD + d;

    // per-channel coefficients
    const float c0 = 1.0f + lfilt[d];
    float a[NTAP];
#pragma unroll
    for (int k = 0; k < NTAP; ++k) a[k] = lfilt[(k + 1) * DD + d];
    const float r0 = rfilt[d];
    const float r1 = rfilt[DD + d];

    // circular history of p (hist[t & 15] = p[t]); zeros = state before ts
    float hist[16];
#pragma unroll
    for (int i = 0; i < 16; ++i) hist[i] = 0.0f;

    // prologue: w0=v[ts], w1=v[ts+1], A0[u]=v[ts+2+u]
    float A0[16], A1[16];
    float w0 = vp[(size_t)ts * DD];
    float w1 = vp[(size_t)(ts + 1) * DD];
#pragma unroll
    for (int u = 0; u < 16; ++u) {
        const int idx = ts + 2 + u;
        A0[u] = (idx < TT) ? vp[(size_t)idx * DD] : 0.0f;
    }

    int tb = ts;
    // warmup: run recurrence, no stores
    for (; tb < t_begin; tb += 32) {
        DFSMN_BLOCK(A0, A1, tb, false)
        DFSMN_BLOCK(A1, A0, tb + 16, false)
    }
    // main: compute + store
    for (; tb < t_end; tb += 32) {
        DFSMN_BLOCK(A0, A1, tb, true)
        DFSMN_BLOCK(A1, A0, tb + 16, true)
    }
}

extern "C" void kernel_launch(void* const* d_in, const int* in_sizes, int n_in,
                              void* d_out, int out_size, void* d_ws, size_t ws_size,
                              hipStream_t stream) {
    const float* v  = (const float*)d_in[0];
    const float* lf = (const float*)d_in[1];
    const float* rf = (const float*)d_in[2];
    float* out = (float*)d_out;

    dim3 grid(DD / 256, BB * HH, TT / CHUNK);
    dim3 block(256, 1, 1);
    dfsmn_kernel<<<grid, block, 0, stream>>>(v, lf, rf, out);
}

// Round 4
// 56.601 us; speedup vs baseline: 1.2248x; 1.2248x over previous
//
#include <hip/hip_runtime.h>

#define BB 16
#define HH 4
#define TT 1024
#define DD 512
#define NTAP 9
#define CHUNK 256
#define LOOKBACK 256

// One thread per (b,h,d) channel; 512-thread blocks cover a FULL d-row so the
// block's aggregate access is sequential 2KB-row streaming (HBM row locality).
// Raw s_barrier (no vmcnt drain!) after each 16-load issue keeps the 8 waves'
// access window tight. Block order z*64+bh co-locates all chunks of one (b,h)
// on the same XCD for L2 sharing of warmup re-reads.
// T split into 4 chunks of 256 with 256-step zero-state warmup (contracting
// recurrence; measured trunc error 0.0156 << 0.121 threshold).

#define DFSMN_BLOCK(CUR, NXT, TB, STORE)                                     \
  {                                                                          \
    _Pragma("unroll")                                                        \
    for (int u = 0; u < 16; ++u) {                                           \
      const int idx = (TB) + 18 + u;                                         \
      NXT[u] = (idx < TT) ? vp[(size_t)idx * DD] : 0.0f;                     \
    }                                                                        \
    __builtin_amdgcn_s_barrier();                                            \
    _Pragma("unroll")                                                        \
    for (int u = 0; u < 16; ++u) {                                           \
      const float vt  = (u == 0) ? w0 : ((u == 1) ? w1 : CUR[(u < 2) ? 0 : (u - 2)]); \
      const float vt1 = (u == 0) ? w1 : CUR[(u < 1) ? 0 : (u - 1)];          \
      const float vt2 = CUR[u];                                              \
      float p = fmaf(vt, c0, r0 * vt1);                                      \
      p = fmaf(r1, vt2, p);                                                  \
      /* oldest tap first: p[t-1] dependency stays the LAST fma */           \
      _Pragma("unroll")                                                      \
      for (int k = NTAP - 1; k >= 0; --k)                                    \
        p = fmaf(a[k], hist[(u + 15 - k) & 15], p);                          \
      hist[u & 15] = p;                                                      \
      if (STORE) __builtin_nontemporal_store(p, &op[(size_t)((TB) + u) * DD]); \
    }                                                                        \
    w0 = CUR[14];                                                            \
    w1 = CUR[15];                                                            \
  }

__global__ __launch_bounds__(512, 2) void dfsmn_kernel(
    const float* __restrict__ v,
    const float* __restrict__ lfilt,
    const float* __restrict__ rfilt,
    float* __restrict__ out)
{
    const int d  = threadIdx.x;                      // 0..511 — full row
    const int bh = blockIdx.x & 63;                  // XCD = bh % 8
    const int z  = blockIdx.x >> 6;                  // chunk index 0..3
    const int t_begin = z * CHUNK;
    const int t_end   = t_begin + CHUNK;
    const int ts = (t_begin >= LOOKBACK) ? (t_begin - LOOKBACK) : 0;

    const float* __restrict__ vp = v + (size_t)bh * TT * DD + d;
    float* __restrict__ op = out + (size_t)bh * TT * DD + d;

    // per-channel coefficients
    const float c0 = 1.0f + lfilt[d];
    float a[NTAP];
#pragma unroll
    for (int k = 0; k < NTAP; ++k) a[k] = lfilt[(k + 1) * DD + d];
    const float r0 = rfilt[d];
    const float r1 = rfilt[DD + d];

    // circular history of p (hist[t & 15] = p[t]); zeros = state before ts
    float hist[16];
#pragma unroll
    for (int i = 0; i < 16; ++i) hist[i] = 0.0f;

    // prologue: w0=v[ts], w1=v[ts+1], A0[u]=v[ts+2+u]
    float A0[16], A1[16];
    float w0 = vp[(size_t)ts * DD];
    float w1 = vp[(size_t)(ts + 1) * DD];
#pragma unroll
    for (int u = 0; u < 16; ++u) {
        const int idx = ts + 2 + u;
        A0[u] = (idx < TT) ? vp[(size_t)idx * DD] : 0.0f;
    }

    int tb = ts;
    // warmup: run recurrence, no stores
    for (; tb < t_begin; tb += 32) {
        DFSMN_BLOCK(A0, A1, tb, false)
        DFSMN_BLOCK(A1, A0, tb + 16, false)
    }
    // main: compute + store
    for (; tb < t_end; tb += 32) {
        DFSMN_BLOCK(A0, A1, tb, true)
        DFSMN_BLOCK(A1, A0, tb + 16, true)
    }
}

extern "C" void kernel_launch(void* const* d_in, const int* in_sizes, int n_in,
                              void* d_out, int out_size, void* d_ws, size_t ws_size,
                              hipStream_t stream) {
    const float* v  = (const float*)d_in[0];
    const float* lf = (const float*)d_in[1];
    const float* rf = (const float*)d_in[2];
    float* out = (float*)d_out;

    dim3 grid((TT / CHUNK) * BB * HH, 1, 1);   // idx = z*64 + bh
    dim3 block(512, 1, 1);
    dfsmn_kernel<<<grid, block, 0, stream>>>(v, lf, rf, out);
}

// Round 5
// 52.711 us; speedup vs baseline: 1.3152x; 1.0738x over previous
//
#include <hip/hip_runtime.h>

#define BB 16
#define HH 4
#define TT 1024
#define DD 512
#define NTAP 9

// Exact, no chunking: one thread per (b,h,d) channel runs the full T=1024
// recurrence. 256 blocks x 128 threads = 1 block/CU; demand = true floor
// 268 MB (134 read + 134 write). 32-deep double-buffered register prefetch
// (issue->use distance ~900 cyc = HBM latency). Static-index circular
// history (rule #20).

#define DFSMN_BLOCK(CUR, NXT, TB, STORE)                                     \
  {                                                                          \
    _Pragma("unroll")                                                        \
    for (int u = 0; u < 32; ++u) {                                           \
      const int idx = (TB) + 34 + u;                                         \
      NXT[u] = (idx < TT) ? vp[(size_t)idx * DD] : 0.0f;                     \
    }                                                                        \
    _Pragma("unroll")                                                        \
    for (int u = 0; u < 32; ++u) {                                           \
      const float vt  = (u == 0) ? w0 : ((u == 1) ? w1 : CUR[(u < 2) ? 0 : (u - 2)]); \
      const float vt1 = (u == 0) ? w1 : CUR[(u < 1) ? 0 : (u - 1)];          \
      const float vt2 = CUR[u];                                              \
      float p = fmaf(vt, c0, r0 * vt1);                                      \
      p = fmaf(r1, vt2, p);                                                  \
      /* oldest tap first: p[t-1] dependency stays the LAST fma */           \
      _Pragma("unroll")                                                      \
      for (int k = NTAP - 1; k >= 0; --k)                                    \
        p = fmaf(a[k], hist[(u + 15 - k) & 15], p);                          \
      hist[u & 15] = p;                                                      \
      if (STORE) __builtin_nontemporal_store(p, &op[(size_t)((TB) + u) * DD]); \
    }                                                                        \
    w0 = CUR[30];                                                            \
    w1 = CUR[31];                                                            \
  }

__global__ __launch_bounds__(128, 1) void dfsmn_kernel(
    const float* __restrict__ v,
    const float* __restrict__ lfilt,
    const float* __restrict__ rfilt,
    float* __restrict__ out)
{
    const int d  = blockIdx.x * 128 + threadIdx.x;   // 0..511
    const int bh = blockIdx.y;                       // 0..63

    const float* __restrict__ vp = v + (size_t)bh * TT * DD + d;
    float* __restrict__ op = out + (size_t)bh * TT * DD + d;

    // per-channel coefficients
    const float c0 = 1.0f + lfilt[d];
    float a[NTAP];
#pragma unroll
    for (int k = 0; k < NTAP; ++k) a[k] = lfilt[(k + 1) * DD + d];
    const float r0 = rfilt[d];
    const float r1 = rfilt[DD + d];

    // circular history of p (hist[t & 15] = p[t]); zeros before t=0
    float hist[16];
#pragma unroll
    for (int i = 0; i < 16; ++i) hist[i] = 0.0f;

    // prologue: w0=v[0], w1=v[1], A0[u]=v[2+u]
    float A0[32], A1[32];
    float w0 = vp[0];
    float w1 = vp[(size_t)1 * DD];
#pragma unroll
    for (int u = 0; u < 32; ++u) {
        A0[u] = vp[(size_t)(2 + u) * DD];   // 2+31 = 33 < 1024, no guard needed
    }

    for (int tb = 0; tb < TT; tb += 64) {
        DFSMN_BLOCK(A0, A1, tb, true)
        DFSMN_BLOCK(A1, A0, tb + 32, true)
    }
}

extern "C" void kernel_launch(void* const* d_in, const int* in_sizes, int n_in,
                              void* d_out, int out_size, void* d_ws, size_t ws_size,
                              hipStream_t stream) {
    const float* v  = (const float*)d_in[0];
    const float* lf = (const float*)d_in[1];
    const float* rf = (const float*)d_in[2];
    float* out = (float*)d_out;

    dim3 grid(DD / 128, BB * HH, 1);
    dim3 block(128, 1, 1);
    dfsmn_kernel<<<grid, block, 0, stream>>>(v, lf, rf, out);
}